// Round 5
// baseline (245.564 us; speedup 1.0000x reference)
//
#include <hip/hip_runtime.h>
#include <stdint.h>

// ---------------------------------------------------------------------------
// SAM encoder attention, MI355X/gfx950.
// convert(fp32->bf16, q pre-scaled by scale*log2e) -> qkv_gemm (glds staging)
// -> rel_kernel (rel_hT transposed, rel_w standard; *8 => *log2e) ->
// flash v3 (k-quarter waves, P-in-registers PV via slot-paired 16x16x32 MFMA
// with zeroed upper j-slots, glds K/V staging, XOR bank swizzle) -> proj_gemm.
// MFMA 16x16x32 bf16 only; layouts per verified m89/m120 mappings:
//   A/B: m(n)=lane&15, k=quad*8+j ; C/D: col=lane&15, row=quad*4+reg.
// ---------------------------------------------------------------------------

typedef unsigned short ushort_t;
typedef __attribute__((ext_vector_type(8))) __bf16 bf16x8;
typedef __attribute__((ext_vector_type(4))) float f32x4;

#define NHD 12
#define HD 64
#define CIN 768
#define HWP 4096
#define QPRE 0.18033688f   /* 0.125 * log2(e) */

#if __has_builtin(__builtin_amdgcn_exp2f)
#define EXP2(x) __builtin_amdgcn_exp2f(x)
#else
#define EXP2(x) exp2f(x)
#endif

__device__ __forceinline__ ushort_t f2bf(float f) {
  union { float f; unsigned u; } v; v.f = f;
  unsigned r = (v.u + 0x7fffu + ((v.u >> 16) & 1u)) >> 16;  // RNE
  return (ushort_t)r;
}
__device__ __forceinline__ float bf2f(ushort_t h) {
  union { unsigned u; float f; } v; v.u = ((unsigned)h) << 16;
  return v.f;
}
__device__ __forceinline__ unsigned packbf(float a, float b) {
  unsigned ua = (__float_as_uint(a) + 0x8000u) >> 16;
  unsigned ub = (__float_as_uint(b) + 0x8000u) & 0xffff0000u;
  return ua | ub;
}
__device__ __forceinline__ f32x4 mfma16(bf16x8 a, bf16x8 b, f32x4 c) {
  return __builtin_amdgcn_mfma_f32_16x16x32_bf16(a, b, c, 0, 0, 0);
}
// bf16x8 with low 2 dwords = (x,y), high 2 dwords = 0 (safe 0*0 in MFMA slots)
__device__ __forceinline__ bf16x8 make8lo(unsigned x, unsigned y) {
  union { uint4 u; bf16x8 v; } t;
  t.u = make_uint4(x, y, 0u, 0u);
  return t.v;
}

// async global->LDS, 16B per lane. LDS dest = wave-uniform base + lane*16.
typedef const __attribute__((address_space(1))) unsigned int* gas_u32p;
typedef __attribute__((address_space(3))) unsigned int* las_u32p;
__device__ __forceinline__ void glds16(const ushort_t* g, ushort_t* l) {
  __builtin_amdgcn_global_load_lds((gas_u32p)g, (las_u32p)l, 16, 0, 0);
}

// ---------------------------------------------------------------------------
// fp32 -> bf16 conversions, vectorized (16B load / 8B store per lane).
// ---------------------------------------------------------------------------
__global__ void convert_kernel(const float* __restrict__ x,
                               const float* __restrict__ wq, const float* __restrict__ bq,
                               const float* __restrict__ wk, const float* __restrict__ bk,
                               const float* __restrict__ wv, const float* __restrict__ bv,
                               const float* __restrict__ rph, const float* __restrict__ rpw,
                               const float* __restrict__ pw,
                               ushort_t* __restrict__ x_bf, ushort_t* __restrict__ w_bf,
                               ushort_t* __restrict__ pw_bf, ushort_t* __restrict__ rph_bf,
                               ushort_t* __restrict__ rpw_bf, float* __restrict__ bias_all) {
  const int i = blockIdx.x * blockDim.x + threadIdx.x;
  const int stride = gridDim.x * blockDim.x;
  const int NX4 = (HWP * CIN) / 4;
  const int NW4 = (NHD * HD * CIN) / 4;
  const int NR4 = (127 * HD) / 4;
  for (int t = i; t < NX4; t += stride) {
    float4 a = ((const float4*)x)[t];
    uint2 o; o.x = packbf(a.x, a.y); o.y = packbf(a.z, a.w);
    ((uint2*)x_bf)[t] = o;
  }
  for (int t = i; t < NW4; t += stride) {
    float4 a = ((const float4*)wq)[t];
    float4 b = ((const float4*)wk)[t];
    float4 c = ((const float4*)wv)[t];
    float4 d = ((const float4*)pw)[t];
    uint2 o;
    o.x = packbf(a.x, a.y); o.y = packbf(a.z, a.w); ((uint2*)w_bf)[t] = o;
    o.x = packbf(b.x, b.y); o.y = packbf(b.z, b.w); ((uint2*)w_bf)[NW4 + t] = o;
    o.x = packbf(c.x, c.y); o.y = packbf(c.z, c.w); ((uint2*)w_bf)[2 * NW4 + t] = o;
    o.x = packbf(d.x, d.y); o.y = packbf(d.z, d.w); ((uint2*)pw_bf)[t] = o;
  }
  for (int t = i; t < NR4; t += stride) {
    float4 a = ((const float4*)rph)[t];
    float4 b = ((const float4*)rpw)[t];
    uint2 o;
    o.x = packbf(a.x, a.y); o.y = packbf(a.z, a.w); ((uint2*)rph_bf)[t] = o;
    o.x = packbf(b.x, b.y); o.y = packbf(b.z, b.w); ((uint2*)rpw_bf)[t] = o;
  }
  for (int t = i; t < NHD * HD; t += stride) {
    bias_all[t]        = bq[t];
    bias_all[768 + t]  = bk[t];
    bias_all[1536 + t] = bv[t];
  }
}

// ---------------------------------------------------------------------------
// QKV GEMM: C(4096x2304) = X * W^T, glds staging, XOR-swizzled [128][32] LDS.
// q stored pre-scaled by QPRE; v packed 8B stores to [n][d][p].
// ---------------------------------------------------------------------------
__global__ __launch_bounds__(256) void qkv_gemm(
    const ushort_t* __restrict__ x_bf, const ushort_t* __restrict__ w_bf,
    const float* __restrict__ bias_all,
    ushort_t* __restrict__ q_bf, ushort_t* __restrict__ k_bf, ushort_t* __restrict__ v_t) {
  __shared__ ushort_t As[128 * 32];
  __shared__ ushort_t Bs[128 * 32];
  const int m0 = blockIdx.x * 128, n0 = blockIdx.y * 128;
  const int tid = threadIdx.x;
  const int lane = tid & 63, wid = tid >> 6;
  const int l15 = lane & 15, quad = lane >> 4;
  const int wm = (wid >> 1) * 64, wn = (wid & 1) * 64;
  const int gr = lane >> 2;
  const int cl = (lane & 3) ^ ((lane >> 3) & 3);
  const int swz = quad ^ ((l15 >> 1) & 3);
  const int Ra = wid * 16;

  f32x4 acc[4][4];
#pragma unroll
  for (int a = 0; a < 4; a++)
#pragma unroll
    for (int b = 0; b < 4; b++) acc[a][b] = (f32x4){0.f, 0.f, 0.f, 0.f};

  for (int kt = 0; kt < 24; kt++) {
    __syncthreads();
    const size_t kofs = (size_t)kt * 32 + cl * 8;
    glds16(&x_bf[(size_t)(m0 + Ra + gr) * CIN + kofs],      &As[Ra * 32]);
    glds16(&x_bf[(size_t)(m0 + 64 + Ra + gr) * CIN + kofs], &As[(64 + Ra) * 32]);
    glds16(&w_bf[(size_t)(n0 + Ra + gr) * CIN + kofs],      &Bs[Ra * 32]);
    glds16(&w_bf[(size_t)(n0 + 64 + Ra + gr) * CIN + kofs], &Bs[(64 + Ra) * 32]);
    __syncthreads();
    bf16x8 af[4], bfr[4];
#pragma unroll
    for (int mb = 0; mb < 4; mb++)
      af[mb] = *reinterpret_cast<const bf16x8*>(&As[(wm + mb * 16 + l15) * 32 + swz * 8]);
#pragma unroll
    for (int nb = 0; nb < 4; nb++)
      bfr[nb] = *reinterpret_cast<const bf16x8*>(&Bs[(wn + nb * 16 + l15) * 32 + swz * 8]);
#pragma unroll
    for (int mb = 0; mb < 4; mb++)
#pragma unroll
      for (int nb = 0; nb < 4; nb++)
        acc[mb][nb] = mfma16(af[mb], bfr[nb], acc[mb][nb]);
  }

#pragma unroll
  for (int mb = 0; mb < 4; mb++) {
#pragma unroll
    for (int nb = 0; nb < 4; nb++) {
      const int colg = n0 + wn + nb * 16 + l15;
      const float bias = bias_all[colg];
      if (colg >= 1536) {
        const int j = colg - 1536;
        uint2 wv2;
        wv2.x = packbf(acc[mb][nb][0] + bias, acc[mb][nb][1] + bias);
        wv2.y = packbf(acc[mb][nb][2] + bias, acc[mb][nb][3] + bias);
        *(uint2*)&v_t[(size_t)j * HWP + m0 + wm + mb * 16 + quad * 4] = wv2;
      } else {
#pragma unroll
        for (int r = 0; r < 4; r++) {
          const int rowg = m0 + wm + mb * 16 + quad * 4 + r;
          const float val = acc[mb][nb][r] + bias;
          if (colg < 768) {
            q_bf[(((size_t)(colg >> 6)) * HWP + rowg) * HD + (colg & 63)] = f2bf(val * QPRE);
          } else {
            const int j = colg - 768;
            k_bf[(((size_t)(j >> 6)) * HWP + rowg) * HD + (j & 63)] = f2bf(val);
          }
        }
      }
    }
  }
}

// ---------------------------------------------------------------------------
// rel tables. mode 0 -> rel_hT[n][h][t][w]; mode 1 -> rel_w[n][p][w2].
// Outputs *8 => rel * log2(e)  (q_bf pre-scaled by QPRE).
// ---------------------------------------------------------------------------
__global__ __launch_bounds__(256) void rel_kernel(
    const ushort_t* __restrict__ q_bf, const ushort_t* __restrict__ rph_bf,
    const ushort_t* __restrict__ rpw_bf,
    ushort_t* __restrict__ rel_hT, ushort_t* __restrict__ rel_w) {
  const int mode = blockIdx.y;
  const ushort_t* __restrict__ rp_bf = mode ? rpw_bf : rph_bf;
  const int bx = blockIdx.x;
  const int n = bx >> 6, hw = bx & 63;
  const int tid = threadIdx.x;
  const int lane = tid & 63, wid = tid >> 6;
  const int l15 = lane & 15, quad = lane >> 4;

  __shared__ ushort_t Qs[64][72];
  __shared__ ushort_t Rs[64][72];

  const int r0 = tid >> 3, c8 = (tid & 7) * 8;
#pragma unroll
  for (int h = 0; h < 2; h++) {
    const int r = r0 + h * 32;
    const int p = (mode == 0) ? (hw * 64 + r) : (r * 64 + hw);
    *(uint4*)&Qs[r][c8] = *(const uint4*)&q_bf[((size_t)n * HWP + p) * HD + c8];
    *(uint4*)&Rs[r][c8] = *(const uint4*)&rp_bf[(63 + hw - r) * HD + c8];
  }
  __syncthreads();

  bf16x8 a0 = *reinterpret_cast<const bf16x8*>(&Qs[wid * 16 + l15][quad * 8]);
  bf16x8 a1 = *reinterpret_cast<const bf16x8*>(&Qs[wid * 16 + l15][32 + quad * 8]);
#pragma unroll
  for (int nb = 0; nb < 4; nb++) {
    bf16x8 b0 = *reinterpret_cast<const bf16x8*>(&Rs[nb * 16 + l15][quad * 8]);
    bf16x8 b1 = *reinterpret_cast<const bf16x8*>(&Rs[nb * 16 + l15][32 + quad * 8]);
    f32x4 c = (f32x4){0.f, 0.f, 0.f, 0.f};
    c = mfma16(a0, b0, c);
    c = mfma16(a1, b1, c);
    const int col = nb * 16 + l15;
    if (mode == 0) {
      uint2 o;
      o.x = packbf(c[0] * 8.0f, c[1] * 8.0f);
      o.y = packbf(c[2] * 8.0f, c[3] * 8.0f);
      *(uint2*)&rel_hT[(((size_t)(n * 64 + hw) * 64) + col) * 64 + wid * 16 + quad * 4] = o;
    } else {
#pragma unroll
      for (int r = 0; r < 4; r++) {
        const int lr = wid * 16 + quad * 4 + r;
        const int p2 = lr * 64 + hw;
        rel_w[((size_t)n * HWP + p2) * 64 + col] = f2bf(c[r] * 8.0f);
      }
    }
  }
}

// ---------------------------------------------------------------------------
// Flash attention v3: block = (head n, q-row qt); 4 waves = k-QUARTERS (wk).
// Per 64-key tile t: wave wk owns K rows wk*16..+15 and k-cols of V.
//   S^T[k][q]: af (16 K-rows, A-frag) x qb[4][2] (Q B-frags in regs) -> 8 MFMA.
//   P stays in REGISTERS: C-layout (q=l15, k=quad*4+r) slots directly into a
//   16x16x32 B-operand's j-slots 0-3 (j-slots 4-7 = 0); V read as b64 into
//   A j-slots 0-3 (4-7 = 0). Slot-paired contraction == exact 16-k dot.
// No P LDS round-trip, no af/vf wave-duplication. LDS ~35 KB.
// Epilogue: cross-wave od reduce via 2-phase fp32 LDS overlay; l via shfl+LDS.
// ---------------------------------------------------------------------------
__global__ __launch_bounds__(256, 3) void flash_kernel(
    const ushort_t* __restrict__ q_bf, const ushort_t* __restrict__ k_bf,
    const ushort_t* __restrict__ v_t, const ushort_t* __restrict__ rel_hT,
    const ushort_t* __restrict__ rel_w, ushort_t* __restrict__ ao_bf) {
  const int bx = blockIdx.x;
  const int n = bx >> 6, qt = bx & 63;
  const int q0 = qt * 64;
  const int tid = threadIdx.x;
  const int lane = tid & 63, wid = tid >> 6;   // wid = wk (k-quarter)
  const int l15 = lane & 15, quad = lane >> 4;

  // LDS: main loop: KsF@0 [64][64] 8KB, VtF@8192 8KB, RWs@16384 8KB.
  // Epilogue overlay: buf0@0 [64][66] f32 (16896B), buf1@16896, Lbuf@33792 [4][64] f32.
  __shared__ __align__(16) char smem[34816];
  ushort_t* KsF = (ushort_t*)smem;
  ushort_t* VtF = (ushort_t*)(smem + 8192);
  ushort_t* RWs = (ushort_t*)(smem + 16384);
  float* buf0 = (float*)smem;
  float* buf1 = (float*)(smem + 16896);
  float* Lbuf = (float*)(smem + 33792);

  const int gr8 = lane >> 3;                       // row within 8-row group
  const int cl8 = (lane & 7) ^ (gr8 & 7);          // swizzled source chunk
  const int rsw = l15 & 7;                         // read-side swizzle key

  // ---- stage Q (into KsF, swizzled) + RWs (plain) ----
  {
    const size_t qbase = ((size_t)n * HWP + q0 + gr8) * HD + cl8 * 8;
#pragma unroll
    for (int i = 0; i < 2; i++) {
      const int R0 = wid * 16 + i * 8;
      glds16(&q_bf[qbase + (size_t)R0 * HD], &KsF[R0 * 64]);
    }
    const int r0 = tid >> 3, c8 = (tid & 7) * 8;
#pragma unroll
    for (int h = 0; h < 2; h++) {
      const int r = r0 + h * 32;
      *(uint4*)&RWs[r * 64 + c8] = *(const uint4*)&rel_w[(((size_t)n * HWP + q0 + r) << 6) + c8];
    }
  }
  __syncthreads();

  bf16x8 qb[4][2];
#pragma unroll
  for (int b = 0; b < 4; b++)
#pragma unroll
    for (int s = 0; s < 2; s++)
      qb[b][s] = *reinterpret_cast<const bf16x8*>(
          &KsF[(b * 16 + l15) * 64 + (((s * 4 + quad) ^ rsw) * 8)]);
  __syncthreads();   // qb reads done before K tile 0 overwrites KsF

  auto stageKV = [&](int tt) {
    const size_t kbase = ((size_t)n * HWP + (size_t)tt * 64 + gr8) * HD + cl8 * 8;
#pragma unroll
    for (int i = 0; i < 2; i++) {
      const int R0 = wid * 16 + i * 8;
      glds16(&k_bf[kbase + (size_t)R0 * HD], &KsF[R0 * 64]);
    }
    const size_t vbase = ((size_t)n * HD + gr8) * HWP + (size_t)tt * 64 + cl8 * 8;
#pragma unroll
    for (int i = 0; i < 2; i++) {
      const int R0 = wid * 16 + i * 8;
      glds16(&v_t[vbase + (size_t)R0 * HWP], &VtF[R0 * 64]);
    }
  };
  stageKV(0);

  // rel_hT prefetch (4 scalars/lane/tile: one per q-block)
  const ushort_t* rhbase = rel_hT + (((size_t)n * 64 + qt) << 12);
  ushort_t rhreg[4];
#pragma unroll
  for (int b = 0; b < 4; b++) rhreg[b] = rhbase[b * 16 + l15];

  f32x4 od[4][4];                 // [dt][qb]: d = dt*16+quad*4+r, q = qb*16+l15
#pragma unroll
  for (int dt = 0; dt < 4; dt++)
#pragma unroll
    for (int b = 0; b < 4; b++) od[dt][b] = (f32x4){0.f, 0.f, 0.f, 0.f};
  float l_lane[4] = {0.f, 0.f, 0.f, 0.f};

  // vf address: V^T row d, cols wk*16+quad*4 (8B) with chunk swizzle
  const int vchunk = (wid * 2 + (quad >> 1));
  const int vhalf = (quad & 1) * 4;

  for (int t = 0; t < 64; t++) {
    __syncthreads();   // B1: DMA(t) complete (vmcnt drained at barrier)

    bf16x8 af[2];
#pragma unroll
    for (int s = 0; s < 2; s++)
      af[s] = *reinterpret_cast<const bf16x8*>(
          &KsF[(wid * 16 + l15) * 64 + (((s * 4 + quad) ^ rsw) * 8)]);
    uint2 vlo[4];
#pragma unroll
    for (int dt = 0; dt < 4; dt++)
      vlo[dt] = *(const uint2*)&VtF[(dt * 16 + l15) * 64 + ((vchunk ^ rsw) * 8 + vhalf)];

    __syncthreads();   // B2: all Ks/Vt reads done
    if (t < 63) stageKV(t + 1);   // DMA overlaps all compute below

    // --- S^T = K(16 rows) x Q^T (64 q) ---
    f32x4 sT[4];
#pragma unroll
    for (int b = 0; b < 4; b++) sT[b] = (f32x4){0.f, 0.f, 0.f, 0.f};
#pragma unroll
    for (int s = 0; s < 2; s++)
#pragma unroll
      for (int b = 0; b < 4; b++)
        sT[b] = mfma16(af[s], qb[b][s], sT[b]);

    // --- bias factors ---
    float rw[4];
    {
      uint2 u = *(const uint2*)&RWs[t * 64 + wid * 16 + quad * 4];
      rw[0] = __uint_as_float(u.x << 16);
      rw[1] = __uint_as_float(u.x & 0xffff0000u);
      rw[2] = __uint_as_float(u.y << 16);
      rw[3] = __uint_as_float(u.y & 0xffff0000u);
    }
    float rhf[4];
#pragma unroll
    for (int b = 0; b < 4; b++) rhf[b] = bf2f(rhreg[b]);
    if (t < 63) {
#pragma unroll
      for (int b = 0; b < 4; b++) rhreg[b] = rhbase[(t + 1) * 64 + b * 16 + l15];
    }

    // --- exp2 + pack + l + PV (all in registers) ---
    bf16x8 vfA[4];
#pragma unroll
    for (int dt = 0; dt < 4; dt++) vfA[dt] = make8lo(vlo[dt].x, vlo[dt].y);
#pragma unroll
    for (int b = 0; b < 4; b++) {
      const float p0 = EXP2(sT[b][0] + rhf[b] + rw[0]);
      const float p1 = EXP2(sT[b][1] + rhf[b] + rw[1]);
      const float p2 = EXP2(sT[b][2] + rhf[b] + rw[2]);
      const float p3 = EXP2(sT[b][3] + rhf[b] + rw[3]);
      l_lane[b] += (p0 + p1) + (p2 + p3);
      const bf16x8 pB = make8lo(packbf(p0, p1), packbf(p2, p3));
#pragma unroll
      for (int dt = 0; dt < 4; dt++)
        od[dt][b] = mfma16(vfA[dt], pB, od[dt][b]);
    }
  }

  // --- l: reduce over quads (shfl); publish per-wave partial to Lbuf ---
#pragma unroll
  for (int b = 0; b < 4; b++) {
    l_lane[b] += __shfl_xor(l_lane[b], 16, 64);
    l_lane[b] += __shfl_xor(l_lane[b], 32, 64);
  }
  __syncthreads();   // loop's LDS reads done before overlay
  if (lane < 16) {
#pragma unroll
    for (int b = 0; b < 4; b++)
      Lbuf[wid * 64 + b * 16 + lane] = l_lane[b];
  }
  // --- od: 2-phase cross-wave reduce (waves 0,1 write; 2,3 add) ---
  float* mybuf = (wid & 1) ? buf1 : buf0;
  if (wid < 2) {
#pragma unroll
    for (int dt = 0; dt < 4; dt++)
#pragma unroll
      for (int b = 0; b < 4; b++)
        *(f32x4*)&mybuf[(b * 16 + l15) * 66 + dt * 16 + quad * 4] = od[dt][b];
  }
  __syncthreads();
  if (wid >= 2) {
#pragma unroll
    for (int dt = 0; dt < 4; dt++)
#pragma unroll
      for (int b = 0; b < 4; b++) {
        float* p = &mybuf[(b * 16 + l15) * 66 + dt * 16 + quad * 4];
        f32x4 cur = *(f32x4*)p;
        cur += od[dt][b];
        *(f32x4*)p = cur;
      }
  }
  __syncthreads();

  // --- cooperative epilogue: o = (buf0+buf1)/l, coalesced bf16 stores ---
  {
    const int q = tid >> 2, db = (tid & 3) * 16;
    const float linv = 1.0f / (Lbuf[q] + Lbuf[64 + q] + Lbuf[128 + q] + Lbuf[192 + q]);
    unsigned outd[8];
#pragma unroll
    for (int j = 0; j < 8; j++) {
      const int d0 = db + 2 * j;
      const float v0 = (buf0[q * 66 + d0] + buf1[q * 66 + d0]) * linv;
      const float v1 = (buf0[q * 66 + d0 + 1] + buf1[q * 66 + d0 + 1]) * linv;
      outd[j] = (unsigned)f2bf(v0) | ((unsigned)f2bf(v1) << 16);
    }
    uint4 s0 = make_uint4(outd[0], outd[1], outd[2], outd[3]);
    uint4 s1 = make_uint4(outd[4], outd[5], outd[6], outd[7]);
    *(uint4*)&ao_bf[(size_t)(q0 + q) * 768 + n * 64 + db]     = s0;
    *(uint4*)&ao_bf[(size_t)(q0 + q) * 768 + n * 64 + db + 8] = s1;
  }
}

// ---------------------------------------------------------------------------
// Output projection, glds/swizzle structure, fp32 out.
// ---------------------------------------------------------------------------
__global__ __launch_bounds__(256) void proj_gemm(
    const ushort_t* __restrict__ ao_bf, const ushort_t* __restrict__ pw_bf,
    const float* __restrict__ pb, float* __restrict__ out) {
  __shared__ ushort_t As[128 * 32];
  __shared__ ushort_t Bs[128 * 32];
  const int m0 = blockIdx.x * 128, n0 = blockIdx.y * 128;
  const int tid = threadIdx.x;
  const int lane = tid & 63, wid = tid >> 6;
  const int l15 = lane & 15, quad = lane >> 4;
  const int wm = (wid >> 1) * 64, wn = (wid & 1) * 64;
  const int gr = lane >> 2;
  const int cl = (lane & 3) ^ ((lane >> 3) & 3);
  const int swz = quad ^ ((l15 >> 1) & 3);
  const int Ra = wid * 16;

  f32x4 acc[4][4];
#pragma unroll
  for (int a = 0; a < 4; a++)
#pragma unroll
    for (int b = 0; b < 4; b++) acc[a][b] = (f32x4){0.f, 0.f, 0.f, 0.f};

  for (int kt = 0; kt < 24; kt++) {
    __syncthreads();
    const size_t kofs = (size_t)kt * 32 + cl * 8;
    glds16(&ao_bf[(size_t)(m0 + Ra + gr) * CIN + kofs],      &As[Ra * 32]);
    glds16(&ao_bf[(size_t)(m0 + 64 + Ra + gr) * CIN + kofs], &As[(64 + Ra) * 32]);
    glds16(&pw_bf[(size_t)(n0 + Ra + gr) * CIN + kofs],      &Bs[Ra * 32]);
    glds16(&pw_bf[(size_t)(n0 + 64 + Ra + gr) * CIN + kofs], &Bs[(64 + Ra) * 32]);
    __syncthreads();
    bf16x8 af[4], bfr[4];
#pragma unroll
    for (int mb = 0; mb < 4; mb++)
      af[mb] = *reinterpret_cast<const bf16x8*>(&As[(wm + mb * 16 + l15) * 32 + swz * 8]);
#pragma unroll
    for (int nb = 0; nb < 4; nb++)
      bfr[nb] = *reinterpret_cast<const bf16x8*>(&Bs[(wn + nb * 16 + l15) * 32 + swz * 8]);
#pragma unroll
    for (int mb = 0; mb < 4; mb++)
#pragma unroll
      for (int nb = 0; nb < 4; nb++)
        acc[mb][nb] = mfma16(af[mb], bfr[nb], acc[mb][nb]);
  }

#pragma unroll
  for (int mb = 0; mb < 4; mb++) {
#pragma unroll
    for (int nb = 0; nb < 4; nb++) {
      const int colg = n0 + wn + nb * 16 + l15;
      const float bias = pb[colg];
#pragma unroll
      for (int r = 0; r < 4; r++) {
        const int rowg = m0 + wm + mb * 16 + quad * 4 + r;
        out[(size_t)rowg * 768 + colg] = acc[mb][nb][r] + bias;
      }
    }
  }
}

// ---------------------------------------------------------------------------
extern "C" void kernel_launch(void* const* d_in, const int* in_sizes, int n_in,
                              void* d_out, int out_size, void* d_ws, size_t ws_size,
                              hipStream_t stream) {
  (void)in_sizes; (void)n_in; (void)out_size; (void)ws_size;
  const float* x   = (const float*)d_in[0];
  const float* wq  = (const float*)d_in[1];
  const float* bq  = (const float*)d_in[2];
  const float* wk  = (const float*)d_in[3];
  const float* bk  = (const float*)d_in[4];
  const float* wv  = (const float*)d_in[5];
  const float* bv  = (const float*)d_in[6];
  const float* rph = (const float*)d_in[7];
  const float* rpw = (const float*)d_in[8];
  const float* pw  = (const float*)d_in[9];
  const float* pb  = (const float*)d_in[10];
  float* out = (float*)d_out;

  char* ws = (char*)d_ws;
  size_t off = 0;
  auto alloc = [&](size_t bytes) -> char* {
    char* p = ws + off;
    off += (bytes + 255) & ~(size_t)255;
    return p;
  };
  ushort_t* x_bf   = (ushort_t*)alloc((size_t)HWP * CIN * 2);
  ushort_t* w_bf   = (ushort_t*)alloc((size_t)3 * NHD * HD * CIN * 2);
  ushort_t* pw_bf  = (ushort_t*)alloc((size_t)NHD * HD * CIN * 2);
  ushort_t* rph_bf = (ushort_t*)alloc((size_t)127 * HD * 2);
  ushort_t* rpw_bf = (ushort_t*)alloc((size_t)127 * HD * 2);
  float*    bias_all = (float*)alloc((size_t)3 * NHD * HD * 4);
  ushort_t* q_bf   = (ushort_t*)alloc((size_t)NHD * HWP * HD * 2);
  ushort_t* k_bf   = (ushort_t*)alloc((size_t)NHD * HWP * HD * 2);
  ushort_t* v_t    = (ushort_t*)alloc((size_t)NHD * HWP * HD * 2);
  ushort_t* rel_hT = (ushort_t*)alloc((size_t)NHD * HWP * 64 * 2);
  ushort_t* rel_w  = (ushort_t*)alloc((size_t)NHD * HWP * 64 * 2);
  ushort_t* ao_bf  = (ushort_t*)alloc((size_t)HWP * CIN * 2);

  convert_kernel<<<dim3(2048), dim3(256), 0, stream>>>(
      x, wq, bq, wk, bk, wv, bv, rph, rpw, pw,
      x_bf, w_bf, pw_bf, rph_bf, rpw_bf, bias_all);
  qkv_gemm<<<dim3(32, 18), dim3(256), 0, stream>>>(
      x_bf, w_bf, bias_all, q_bf, k_bf, v_t);
  rel_kernel<<<dim3(NHD * 64, 2), dim3(256), 0, stream>>>(
      q_bf, rph_bf, rpw_bf, rel_hT, rel_w);
  flash_kernel<<<dim3(NHD * 64), dim3(256), 0, stream>>>(
      q_bf, k_bf, v_t, rel_hT, rel_w, ao_bf);
  proj_gemm<<<dim3(32, 6), dim3(256), 0, stream>>>(ao_bf, pw_bf, pb, out);
}